// Round 6
// baseline (125.297 us; speedup 1.0000x reference)
//
#include <hip/hip_runtime.h>

#define K 32
#define NB 8
#define MAXM 160   // >= max groups per batch range (~2300/16); masks can't exceed this

// One-shot: bounds[b] = lower_bound(batch_src, b); bounds[NB] = n_src.
__global__ void bounds_kernel(const int* __restrict__ batch_src, int n_src,
                              int* __restrict__ bounds) {
    const int b = threadIdx.x;
    if (b > NB) return;
    int lo = 0, hi = n_src;
    while (lo < hi) {
        int mid = (lo + hi) >> 1;
        if (batch_src[mid] < b) lo = mid + 1; else hi = mid;
    }
    bounds[b] = lo;
}

// Wave serves 4 dsts (quadrants of 16 lanes). All quadrants test the SAME 16
// candidates per step -> 16 unique addresses per load (~10 L1 lines / 64
// pair-tests vs 36 for wave-per-dst). Hits recorded as ballot masks only
// (scalar-lean); epilogue converts per-quadrant 16-bit slices to indices.
__global__ __launch_bounds__(256) void radius_kernel(
    const float* __restrict__ src_xyz,
    const float* __restrict__ dst_xyz, const int* __restrict__ batch_dst,
    const int* __restrict__ bounds, int n_src, int n_dst,
    int* __restrict__ out)
{
    __shared__ unsigned long long s_mask[4][MAXM];
    __shared__ int                s_tb[4][MAXM];
    __shared__ int                s_sel[4][4][K];

    const int w    = threadIdx.x >> 6;        // wave slot in block
    const int lane = threadIdx.x & 63;
    const int q    = lane >> 4;               // quadrant -> which dst
    const int r    = lane & 15;               // candidate sub-index
    const int wave = (blockIdx.x * blockDim.x + threadIdx.x) >> 6;
    const int d    = wave * 4 + q;
    const int dc   = d < n_dst ? d : n_dst - 1;   // dead lanes mirror last dst

    // dst point + |dst|^2, reference-exact fp32 (left-to-right, no FMA).
    const float xd = dst_xyz[3 * dc + 0];
    const float yd = dst_xyz[3 * dc + 1];
    const float zd = dst_xyz[3 * dc + 2];
    const float d2 = __fadd_rn(__fadd_rn(__fmul_rn(xd, xd), __fmul_rn(yd, yd)),
                               __fmul_rn(zd, zd));
    const int b     = batch_dst[dc];
    const int my_lo = bounds[b];
    const int my_hi = bounds[b + 1];

    // Wave scan range = union of quadrant windows (batches sorted: lane0 has
    // min lo, lane63 max hi; union contiguous).
    const int lo_w = __shfl(my_lo, 0);
    const int hi_w = __shfl(my_hi, 63);

    const unsigned long long qmask = 0xFFFFull << (q * 16);
    int count = 0;            // per-lane; uniform within a quadrant
    int nm    = 0;            // wave-uniform stored-mask count

    if (lo_w < hi_w) {
        int tile = lo_w;
        // prologue: load group 0 (clamped addresses, always legal)
        int c  = tile + r;
        int cc = c < n_src - 1 ? c : n_src - 1;
        float xs = src_xyz[3 * cc + 0];
        float ys = src_xyz[3 * cc + 1];
        float zs = src_xyz[3 * cc + 2];
        while (true) {
            // prefetch next group BEFORE this group's ballot/exit decision
            const int c2  = tile + 16 + r;
            const int cc2 = c2 < n_src - 1 ? c2 : n_src - 1;
            const float xs2 = src_xyz[3 * cc2 + 0];
            const float ys2 = src_xyz[3 * cc2 + 1];
            const float zs2 = src_xyz[3 * cc2 + 2];

            // distance, reference-exact fp32 rounding
            const float s2 = __fadd_rn(
                __fadd_rn(__fmul_rn(xs, xs), __fmul_rn(ys, ys)),
                __fmul_rn(zs, zs));
            const float cross = __fadd_rn(
                __fadd_rn(__fmul_rn(xd, xs), __fmul_rn(yd, ys)),
                __fmul_rn(zd, zs));
            const float dist2 = __fsub_rn(__fadd_rn(d2, s2),
                                          __fmul_rn(2.0f, cross));
            // window check handles quadrant batch straddle + dead lanes
            const bool valid = (c >= my_lo) && (c < my_hi) && (dist2 <= 0.04f);
            const unsigned long long m = __ballot(valid);
            if (m != 0ull) {                       // wave-uniform branch
                if (lane == 0) { s_mask[w][nm] = m; s_tb[w][nm] = tile; }
                ++nm;
                count += (int)__popcll(m & qmask);
            }
            const bool fin = (count >= K) || (tile + 16 >= my_hi);
            tile += 16;
            if (__all(fin) || tile >= hi_w) break;
            c = c2; xs = xs2; ys = ys2; zs = zs2;
        }
    }

    // ---- epilogue (wave-private; no __syncthreads needed) ----
    // init all 4*K slots to -1
    ((int*)s_sel[w])[lane] = -1;
    ((int*)s_sel[w])[64 + lane] = -1;

    // For each dst, 64 lanes process stored masks in parallel: lane i takes
    // mask i's 16-bit quadrant slice; prefix-scan of popcounts gives each
    // bit's global rank; emit ranks < K into s_sel.
    for (int qq = 0; qq < 4; ++qq) {
        int done = 0;
        for (int m0 = 0; m0 < nm; m0 += 64) {
            const int i = m0 + lane;
            unsigned slice = 0; int tb = 0;
            if (i < nm) {
                slice = (unsigned)((s_mask[w][i] >> (qq * 16)) & 0xFFFFull);
                tb = s_tb[w][i];
            }
            const int cpc = __popc(slice);
            int pref = cpc;                       // inclusive scan
            #pragma unroll
            for (int off = 1; off < 64; off <<= 1) {
                const int t = __shfl_up(pref, off);
                if (lane >= off) pref += t;
            }
            int rank = done + pref - cpc;         // exclusive start
            unsigned x = slice;
            while (x != 0u && rank < K) {
                const int t = __ffs(x) - 1;       // lowest set bit
                s_sel[w][qq][rank] = tb + t;      // src index = tile + bitpos
                x &= x - 1;
                ++rank;
            }
            done += __shfl(pref, 63);             // total emitted this round
            if (done >= K) break;
        }
    }

    // coalesced output: 2 passes x 64 lanes cover 4 dsts x 32 slots
    const long long nb = (long long)n_dst * K;
    #pragma unroll
    for (int p = 0; p < 2; ++p) {
        const int idx = p * 64 + lane;
        const int qq = idx >> 5, k = idx & 31;
        const int dq = wave * 4 + qq;
        if (dq < n_dst) {
            const int val = s_sel[w][qq][k];
            out[(long long)dq * K + k] = val;                       // edge_src
            out[nb + (long long)dq * K + k] = (val >= 0) ? dq : -1; // edge_dst
        }
    }
}

extern "C" void kernel_launch(void* const* d_in, const int* in_sizes, int n_in,
                              void* d_out, int out_size, void* d_ws, size_t ws_size,
                              hipStream_t stream) {
    const float* src_xyz   = (const float*)d_in[0];
    const int*   batch_src = (const int*)d_in[1];
    const float* dst_xyz   = (const float*)d_in[2];
    const int*   batch_dst = (const int*)d_in[3];
    int* out    = (int*)d_out;
    int* bounds = (int*)d_ws;     // NB+1 ints (int staging: R2/R5-proven)

    const int n_src = in_sizes[0] / 3;
    const int n_dst = in_sizes[2] / 3;

    bounds_kernel<<<1, 16, 0, stream>>>(batch_src, n_src, bounds);

    const int waves  = (n_dst + 3) / 4;           // 4 dsts per wave
    const int blocks = (waves + 3) / 4;           // 4 waves per block
    radius_kernel<<<blocks, 256, 0, stream>>>(
        src_xyz, dst_xyz, batch_dst, bounds, n_src, n_dst, out);
}

// Round 7
// 91.410 us; speedup vs baseline: 1.3707x; 1.3707x over previous
//
#include <hip/hip_runtime.h>

#define K 32
#define NB 8
#define NC 5                      // cells per axis (1/R)
#define NCELL (NC * NC * NC)      // 125
#define TOTC (NB * NCELL)         // 1000
#define MAXW 80                   // bitmap u32 words per dst (2560-index window)

// ws layout (bytes):
//   0     : int bounds[NB+1]
//   64    : int counts[TOTC]
//   4096  : int cellStart[TOTC+1]
//   8192  : int cursor[TOTC]
//   12288 : int sorted_idx[n_src]
//   81920 : float4 sorted_p[n_src]   (16-B aligned)
#define OFF_COUNTS 64
#define OFF_START  4096
#define OFF_CURSOR 8192
#define OFF_SIDX   12288
#define OFF_SP     81920

__device__ __forceinline__ int cell_of(float v) {
    int c = (int)(v * 5.0f);
    return c < 0 ? 0 : (c > NC - 1 ? NC - 1 : c);
}

// K1: zero counters + batch bounds (binary search).
__global__ void setup_zero(const int* __restrict__ batch_src, int n_src,
                           int* __restrict__ bounds, int* __restrict__ counts) {
    const int i = blockIdx.x * blockDim.x + threadIdx.x;
    if (i < TOTC) counts[i] = 0;
    if (i <= NB) {
        int lo = 0, hi = n_src;
        while (lo < hi) {
            int mid = (lo + hi) >> 1;
            if (batch_src[mid] < i) lo = mid + 1; else hi = mid;
        }
        bounds[i] = lo;
    }
}

// K2: histogram of (batch, cell) keys.
__global__ void setup_hist(const float* __restrict__ src_xyz,
                           const int* __restrict__ batch_src, int n_src,
                           int* __restrict__ counts) {
    const int i = blockIdx.x * blockDim.x + threadIdx.x;
    if (i >= n_src) return;
    const float x = src_xyz[3 * i + 0];
    const float y = src_xyz[3 * i + 1];
    const float z = src_xyz[3 * i + 2];
    const int key = batch_src[i] * NCELL +
                    (cell_of(z) * NC + cell_of(y)) * NC + cell_of(x);
    atomicAdd(&counts[key], 1);
}

// K3: single-block exclusive prefix scan (1024 threads >= TOTC).
__global__ void setup_scan(const int* __restrict__ counts, int n_src,
                           int* __restrict__ cellStart, int* __restrict__ cursor) {
    __shared__ int s[1024];
    const int t = threadIdx.x;
    const int val = (t < TOTC) ? counts[t] : 0;
    s[t] = val;
    __syncthreads();
    for (int off = 1; off < 1024; off <<= 1) {
        const int v = (t >= off) ? s[t - off] : 0;
        __syncthreads();
        s[t] += v;
        __syncthreads();
    }
    if (t < TOTC) { cellStart[t] = s[t] - val; cursor[t] = s[t] - val; }
    if (t == 0) cellStart[TOTC] = n_src;
}

// K4: scatter into cell-sorted order; precompute s2 with the reference-exact
// fp32 chain. (Order within a cell is nondeterministic; the bitmap in the
// main kernel restores exact index order, so this is safe.)
__global__ void setup_scatter(const float* __restrict__ src_xyz,
                              const int* __restrict__ batch_src, int n_src,
                              int* __restrict__ cursor,
                              int* __restrict__ sorted_idx,
                              float4* __restrict__ sorted_p) {
    const int i = blockIdx.x * blockDim.x + threadIdx.x;
    if (i >= n_src) return;
    const float x = src_xyz[3 * i + 0];
    const float y = src_xyz[3 * i + 1];
    const float z = src_xyz[3 * i + 2];
    const int key = batch_src[i] * NCELL +
                    (cell_of(z) * NC + cell_of(y)) * NC + cell_of(x);
    const int pos = atomicAdd(&cursor[key], 1);
    const float s2 = __fadd_rn(__fadd_rn(__fmul_rn(x, x), __fmul_rn(y, y)),
                               __fmul_rn(z, z));
    sorted_idx[pos] = i;
    sorted_p[pos] = make_float4(x, y, z, s2);
}

// Main: wave per dst. Scan 9 contiguous cell-row ranges (x innermost merges
// the 3 x-cells); record hits as bits (orig-lo) in a per-wave LDS bitmap;
// epilogue emits the first K set bits in ascending index order.
__global__ __launch_bounds__(256) void radius_kernel(
    const float* __restrict__ dst_xyz, const int* __restrict__ batch_dst,
    const int* __restrict__ bounds, const int* __restrict__ cellStart,
    const int* __restrict__ sorted_idx, const float4* __restrict__ sorted_p,
    int n_dst, int* __restrict__ out)
{
    __shared__ unsigned int bm[4][MAXW];
    const int w    = threadIdx.x >> 6;
    const int lane = threadIdx.x & 63;
    const int d    = (blockIdx.x * blockDim.x + threadIdx.x) >> 6;
    if (d >= n_dst) return;

    // zero this wave's bitmap (wave-private: no __syncthreads needed)
    bm[w][lane] = 0;
    if (lane < MAXW - 64) bm[w][64 + lane] = 0;

    const float xd = dst_xyz[3 * d + 0];
    const float yd = dst_xyz[3 * d + 1];
    const float zd = dst_xyz[3 * d + 2];
    const float d2 = __fadd_rn(__fadd_rn(__fmul_rn(xd, xd), __fmul_rn(yd, yd)),
                               __fmul_rn(zd, zd));
    const int b  = batch_dst[d];
    const int lo = bounds[b];

    const int cx = cell_of(xd), cy = cell_of(yd), cz = cell_of(zd);
    const int x0 = cx - 1 < 0 ? 0 : cx - 1;
    const int x1 = cx + 1 > NC - 1 ? NC - 1 : cx + 1;
    const int base = b * NCELL;

#pragma unroll
    for (int dz = -1; dz <= 1; ++dz) {
        const int czz = cz + dz;
        if (czz < 0 || czz >= NC) continue;
#pragma unroll
        for (int dy = -1; dy <= 1; ++dy) {
            const int cyy = cy + dy;
            if (cyy < 0 || cyy >= NC) continue;
            const int row = base + (czz * NC + cyy) * NC;
            const int r0 = cellStart[row + x0];
            const int r1 = cellStart[row + x1 + 1];
            for (int p0 = r0; p0 < r1; p0 += 64) {
                const int p = p0 + lane;
                const bool act = p < r1;
                const float4 f = sorted_p[act ? p : r1 - 1];
                const float cross = __fadd_rn(
                    __fadd_rn(__fmul_rn(xd, f.x), __fmul_rn(yd, f.y)),
                    __fmul_rn(zd, f.z));
                const float dist2 = __fsub_rn(__fadd_rn(d2, f.w),
                                              __fmul_rn(2.0f, cross));
                if (act && dist2 <= 0.04f) {   // 0.04f == f32(R*R), R4-proven
                    const unsigned wbit = (unsigned)(sorted_idx[p] - lo);
                    if (wbit < MAXW * 32u)     // safety: window <= 2560 always
                        atomicOr(&bm[w][wbit >> 5], 1u << (wbit & 31));
                }
            }
        }
    }

    // epilogue: lane l owns a 64-bit slice (indices lo+64l .. lo+64l+63)
    unsigned l32 = 0, h32 = 0;
    if (lane < MAXW / 2) { l32 = bm[w][2 * lane]; h32 = bm[w][2 * lane + 1]; }
    unsigned long long slice = ((unsigned long long)h32 << 32) | l32;
    const int pc = __popcll(slice);
    int incl = pc;
#pragma unroll
    for (int off = 1; off < 64; off <<= 1) {
        const int v = __shfl_up(incl, off);
        if (lane >= off) incl += v;
    }
    const int T = __shfl(incl, 63);      // total hits this dst
    int rank = incl - pc;                // exclusive prefix = first rank here
    const long long ob  = (long long)d * K;
    const long long nb_ = (long long)n_dst * K;
    unsigned long long x = slice;
    while (x != 0ull && rank < K) {
        const int pos = __ffsll((unsigned long long)x) - 1;
        out[ob + rank]       = lo + 64 * lane + pos;   // edge_src
        out[nb_ + ob + rank] = d;                      // edge_dst
        x &= x - 1;
        ++rank;
    }
    if (lane >= T && lane < K) {
        out[ob + lane]       = -1;
        out[nb_ + ob + lane] = -1;
    }
}

extern "C" void kernel_launch(void* const* d_in, const int* in_sizes, int n_in,
                              void* d_out, int out_size, void* d_ws, size_t ws_size,
                              hipStream_t stream) {
    const float* src_xyz   = (const float*)d_in[0];
    const int*   batch_src = (const int*)d_in[1];
    const float* dst_xyz   = (const float*)d_in[2];
    const int*   batch_dst = (const int*)d_in[3];
    int* out = (int*)d_out;

    char* ws = (char*)d_ws;
    int*    bounds     = (int*)(ws);
    int*    counts     = (int*)(ws + OFF_COUNTS);
    int*    cellStart  = (int*)(ws + OFF_START);
    int*    cursor     = (int*)(ws + OFF_CURSOR);
    int*    sorted_idx = (int*)(ws + OFF_SIDX);
    float4* sorted_p   = (float4*)(ws + OFF_SP);

    const int n_src = in_sizes[0] / 3;
    const int n_dst = in_sizes[2] / 3;

    setup_zero<<<(TOTC + 255) / 256, 256, 0, stream>>>(batch_src, n_src,
                                                       bounds, counts);
    setup_hist<<<(n_src + 255) / 256, 256, 0, stream>>>(src_xyz, batch_src,
                                                        n_src, counts);
    setup_scan<<<1, 1024, 0, stream>>>(counts, n_src, cellStart, cursor);
    setup_scatter<<<(n_src + 255) / 256, 256, 0, stream>>>(
        src_xyz, batch_src, n_src, cursor, sorted_idx, sorted_p);

    const int blocks = (n_dst * 64 + 255) / 256;   // wave per dst, 4 waves/block
    radius_kernel<<<blocks, 256, 0, stream>>>(
        dst_xyz, batch_dst, bounds, cellStart, sorted_idx, sorted_p,
        n_dst, out);
}